// Round 5
// baseline (1195.568 us; speedup 1.0000x reference)
//
#include <hip/hip_runtime.h>
#include <hip/hip_bf16.h>

#define HD 128
#define SCB 2048   // elements per scan block

typedef __attribute__((ext_vector_type(8))) short short8v;
typedef __attribute__((ext_vector_type(4))) float f32x4;

__device__ __forceinline__ unsigned short f2bf(float f) {
    union { float f; unsigned u; } c; c.f = f;
    unsigned u = c.u;
    return (unsigned short)((u + 0x7fffu + ((u >> 16) & 1u)) >> 16);
}
__device__ __forceinline__ float bf2f(unsigned short b) {
    union { unsigned u; float f; } c; c.u = ((unsigned)b) << 16;
    return c.f;
}

// ---------------------------------------------------------------------------
// MFMA node GEMM, fp32 via bf16 hi/lo split (3 MFMA per logical fp32 MFMA).
// A = [A1|A2] hi/lo bf16 pairs, row-major [N][K]. W transposed [128 j][ldw k],
// hi/lo bf16. Block: 64 rows x 128 cols, 4 waves; wave = 16 rows x 128 cols.
// C/D frag mapping (verified m89): col = lane&15, row = (lane>>4)*4 + reg.
// ---------------------------------------------------------------------------
template<int KSTEPS, int K1, bool HASA2, bool RELU, bool DEGB, bool WF32, bool WBF>
__global__ __launch_bounds__(256) void k_mgemm(
    const unsigned short* __restrict__ A1h, const unsigned short* __restrict__ A1l,
    const unsigned short* __restrict__ A2h, const unsigned short* __restrict__ A2l,
    int K2,
    const unsigned short* __restrict__ Wth, const unsigned short* __restrict__ Wtl,
    int ldw,
    const float* __restrict__ bias,
    const float* __restrict__ bdeg, const float* __restrict__ deg,
    float* __restrict__ Cf, unsigned short* __restrict__ Ch,
    unsigned short* __restrict__ Cl,
    int nrows)
{
    const int tid  = threadIdx.x;
    const int wv   = tid >> 6;
    const int lane = tid & 63;
    const int r    = lane & 15;
    const int g    = lane >> 4;
    const int row16 = blockIdx.x * 64 + wv * 16;
    const int goff = g * 8;

    f32x4 acc[8];
#pragma unroll
    for (int t = 0; t < 8; ++t) acc[t] = (f32x4){0.f, 0.f, 0.f, 0.f};

    int arow = row16 + r;
    if (arow >= nrows) arow = nrows - 1;

    for (int s = 0; s < KSTEPS; ++s) {
        const int k0 = s * 32;
        short8v a_h, a_l;
        if (!HASA2 || k0 < K1) {
            size_t off = (size_t)arow * K1 + (size_t)(k0 + goff);
            a_h = *(const short8v*)(A1h + off);
            a_l = *(const short8v*)(A1l + off);
        } else {
            size_t off = (size_t)arow * K2 + (size_t)(k0 - K1 + goff);
            a_h = *(const short8v*)(A2h + off);
            a_l = *(const short8v*)(A2l + off);
        }
#pragma unroll
        for (int t = 0; t < 8; ++t) {
            size_t woff = (size_t)(t * 16 + r) * ldw + (size_t)(k0 + goff);
            short8v b_h = *(const short8v*)(Wth + woff);
            short8v b_l = *(const short8v*)(Wtl + woff);
            acc[t] = __builtin_amdgcn_mfma_f32_16x16x32_bf16(a_h, b_h, acc[t], 0, 0, 0);
            acc[t] = __builtin_amdgcn_mfma_f32_16x16x32_bf16(a_l, b_h, acc[t], 0, 0, 0);
            acc[t] = __builtin_amdgcn_mfma_f32_16x16x32_bf16(a_h, b_l, acc[t], 0, 0, 0);
        }
    }

    float dgv[4];
#pragma unroll
    for (int i = 0; i < 4; ++i) {
        int row = row16 + g * 4 + i;
        dgv[i] = (DEGB && row < nrows) ? deg[row] : 0.f;
    }
#pragma unroll
    for (int t = 0; t < 8; ++t) {
        int col = t * 16 + r;
        float bb = bias ? bias[col] : 0.f;
        float bd = DEGB ? bdeg[col] : 0.f;
#pragma unroll
        for (int i = 0; i < 4; ++i) {
            int row = row16 + g * 4 + i;
            if (row < nrows) {
                float v = acc[t][i] + bb;
                if (DEGB) v += dgv[i] * bd;
                if (RELU) v = fmaxf(v, 0.f);
                size_t o = (size_t)row * HD + col;
                if (WF32) Cf[o] = v;
                if (WBF) {
                    unsigned short hh = f2bf(v);
                    Ch[o] = hh;
                    Cl[o] = f2bf(v - bf2f(hh));
                }
            }
        }
    }
}

// ---------------------------------------------------------------------------
// Conversions: activations (row-major) and weights (transpose to [j][k])
// ---------------------------------------------------------------------------
__global__ void k_cvtA(const float* __restrict__ src,
                       unsigned short* __restrict__ dh,
                       unsigned short* __restrict__ dl, long n)
{
    long i = (long)blockIdx.x * blockDim.x + threadIdx.x;
    if (i >= n) return;
    float v = src[i];
    unsigned short h = f2bf(v);
    dh[i] = h;
    dl[i] = f2bf(v - bf2f(h));
}

__global__ void k_cvtW(const float* __restrict__ src, long sstride, int K,
                       unsigned short* __restrict__ dh,
                       unsigned short* __restrict__ dl, long dstride)
{
    int l = blockIdx.y;
    int idx = blockIdx.x * 256 + threadIdx.x;
    if (idx >= K * 128) return;
    int k = idx >> 7, j = idx & 127;
    float v = src[(size_t)l * sstride + (size_t)k * 128 + j];
    unsigned short h = f2bf(v);
    size_t o = (size_t)l * dstride + (size_t)j * K + k;
    dh[o] = h;
    dl[o] = f2bf(v - bf2f(h));
}

// ---------------------------------------------------------------------------
// CSR build: deg -> 3-phase parallel scan -> scatter
// ---------------------------------------------------------------------------
__global__ void k_deg(const int* __restrict__ dst, int* __restrict__ degi, int E)
{
    int e = blockIdx.x * blockDim.x + threadIdx.x;
    if (e < E) atomicAdd(&degi[dst[e]], 1);
}

__global__ void k_hist(const int* __restrict__ batch, int* __restrict__ gcnt, int N)
{
    int n = blockIdx.x * blockDim.x + threadIdx.x;
    if (n < N) atomicAdd(&gcnt[batch[n]], 1);
}

__global__ __launch_bounds__(256) void k_scan1(const int* __restrict__ degi,
                                               int* __restrict__ thrpre,
                                               int* __restrict__ bsum, int N)
{
    __shared__ int sc[256];
    const int t = threadIdx.x, b = blockIdx.x;
    int i0 = b * SCB + t * 8;
    int s = 0;
#pragma unroll
    for (int q = 0; q < 8; ++q) {
        int i = i0 + q;
        if (i < N) s += degi[i];
    }
    sc[t] = s;
    __syncthreads();
    for (int o = 1; o < 256; o <<= 1) {
        int v = (t >= o) ? sc[t - o] : 0;
        __syncthreads();
        sc[t] += v;
        __syncthreads();
    }
    thrpre[b * 256 + t] = sc[t] - s;
    if (t == 255) bsum[b] = sc[255];
}

__global__ void k_scan2(const int* __restrict__ bsum, int* __restrict__ boff, int nb)
{
    if (threadIdx.x == 0 && blockIdx.x == 0) {
        int run = 0;
        for (int b = 0; b < nb; ++b) { boff[b] = run; run += bsum[b]; }
    }
}

__global__ __launch_bounds__(256) void k_scan3(
    const int* __restrict__ degi, const int* __restrict__ thrpre,
    const int* __restrict__ boff,
    int* __restrict__ rowptr, int* __restrict__ cursor,
    float* __restrict__ degf, int N, int E)
{
    const int t = threadIdx.x, b = blockIdx.x;
    int run = boff[b] + thrpre[b * 256 + t];
    int i0 = b * SCB + t * 8;
#pragma unroll
    for (int q = 0; q < 8; ++q) {
        int i = i0 + q;
        if (i < N) {
            int d = degi[i];
            rowptr[i] = run;
            cursor[i] = run;
            degf[i] = (float)d;
            run += d;
        }
    }
    if (b == 0 && t == 0) rowptr[N] = E;
}

__global__ void k_scatter(const int* __restrict__ dst, const int* __restrict__ src,
                          int* __restrict__ cursor,
                          int* __restrict__ csr_src, int* __restrict__ csr_eid, int E)
{
    int e = blockIdx.x * blockDim.x + threadIdx.x;
    if (e < E) {
        int d = dst[e];
        int pos = atomicAdd(&cursor[d], 1);
        csr_src[pos] = src[e];
        csr_eid[pos] = e;
    }
}

__global__ void k_permEA(const float* __restrict__ ea, const int* __restrict__ csr_eid,
                         float* __restrict__ ea_p, int E)
{
    long long gid = (long long)blockIdx.x * blockDim.x + threadIdx.x;
    if (gid >= (long long)E * 4) return;
    int pos = (int)(gid >> 2), part = (int)(gid & 3);
    int e = csr_eid[pos];
    ((float4*)ea_p)[(size_t)pos * 4 + part] = ((const float4*)ea)[(size_t)e * 4 + part];
}

// ---------------------------------------------------------------------------
// Weight folds: Wcomb rows 128..255 = W2 @ U1b ; bvec2 = b2 @ U1b
// ---------------------------------------------------------------------------
__global__ __launch_bounds__(256) void k_foldW(
    const float* __restrict__ msg_W2, const float* __restrict__ upd_W1,
    float* __restrict__ Wcomb)
{
    int l = blockIdx.x >> 3, rb = blockIdx.x & 7;
    const float* W2  = msg_W2 + (size_t)l * HD * HD;
    const float* U1b = upd_W1 + (size_t)l * 256 * HD + (size_t)HD * HD;
    float* Wout = Wcomb + (size_t)l * 256 * HD + (size_t)HD * HD;
    int j = threadIdx.x & 127;
    int rh = threadIdx.x >> 7;
    int r0 = rb * 16 + rh * 8;
    float acc[8] = {0.f,0.f,0.f,0.f,0.f,0.f,0.f,0.f};
    for (int k = 0; k < HD; ++k) {
        float u = U1b[(size_t)k * HD + j];
#pragma unroll
        for (int rr = 0; rr < 8; ++rr)
            acc[rr] = fmaf(W2[(size_t)(r0 + rr) * HD + k], u, acc[rr]);
    }
#pragma unroll
    for (int rr = 0; rr < 8; ++rr)
        Wout[(size_t)(r0 + rr) * HD + j] = acc[rr];
}

__global__ __launch_bounds__(128) void k_foldb(
    const float* __restrict__ msg_b2, const float* __restrict__ upd_W1,
    float* __restrict__ bvec2)
{
    int l = blockIdx.x, j = threadIdx.x;
    const float* U1b = upd_W1 + (size_t)l * 256 * HD + (size_t)HD * HD;
    const float* b2 = msg_b2 + (size_t)l * HD;
    float acc = 0.f;
    for (int k = 0; k < HD; ++k) acc = fmaf(b2[k], U1b[(size_t)k * HD + j], acc);
    bvec2[(size_t)l * HD + j] = acc;
}

// ---------------------------------------------------------------------------
// Edge gather: S[n] = sum_{e:dst=n} relu(P[n] + Q[src] + ea@Wc)
// wave per node; 4-edge unroll. Output written as bf16 hi/lo pair.
// ---------------------------------------------------------------------------
template<bool PERM>
__global__ __launch_bounds__(256) void k_edge(
    const float* __restrict__ P, const float* __restrict__ Q,
    const float* __restrict__ EA,
    const int* __restrict__ rowptr,
    const int* __restrict__ csr_src, const int* __restrict__ csr_eid,
    const float* __restrict__ W1c,
    unsigned short* __restrict__ Sh, unsigned short* __restrict__ Sl, int N)
{
    const int lane = threadIdx.x & 63;
    const int node = blockIdx.x * 4 + (threadIdx.x >> 6);
    if (node >= N) return;
    float wA[16], wB[16];
#pragma unroll
    for (int k = 0; k < 16; ++k) {
        wA[k] = W1c[k * HD + lane];
        wB[k] = W1c[k * HD + 64 + lane];
    }
    const int beg = rowptr[node], end = rowptr[node + 1];
    const float pA = P[(size_t)node * HD + lane];
    const float pB = P[(size_t)node * HD + 64 + lane];
    float accA = 0.f, accB = 0.f;

    int i = beg;
    for (; i + 4 <= end; i += 4) {
        int s[4];
        s[0] = csr_src[i]; s[1] = csr_src[i + 1];
        s[2] = csr_src[i + 2]; s[3] = csr_src[i + 3];
        float qA[4], qB[4];
#pragma unroll
        for (int r2 = 0; r2 < 4; ++r2) {
            qA[r2] = Q[(size_t)s[r2] * HD + lane];
            qB[r2] = Q[(size_t)s[r2] * HD + 64 + lane];
        }
#pragma unroll
        for (int r2 = 0; r2 < 4; ++r2) {
            const float4* Ev = PERM ? (const float4*)&EA[(size_t)(i + r2) * 16]
                                    : (const float4*)&EA[(size_t)csr_eid[i + r2] * 16];
            float4 v0 = Ev[0], v1 = Ev[1], v2 = Ev[2], v3 = Ev[3];
            float tA = pA + qA[r2], tB = pB + qB[r2];
            tA = fmaf(v0.x, wA[0],  tA); tB = fmaf(v0.x, wB[0],  tB);
            tA = fmaf(v0.y, wA[1],  tA); tB = fmaf(v0.y, wB[1],  tB);
            tA = fmaf(v0.z, wA[2],  tA); tB = fmaf(v0.z, wB[2],  tB);
            tA = fmaf(v0.w, wA[3],  tA); tB = fmaf(v0.w, wB[3],  tB);
            tA = fmaf(v1.x, wA[4],  tA); tB = fmaf(v1.x, wB[4],  tB);
            tA = fmaf(v1.y, wA[5],  tA); tB = fmaf(v1.y, wB[5],  tB);
            tA = fmaf(v1.z, wA[6],  tA); tB = fmaf(v1.z, wB[6],  tB);
            tA = fmaf(v1.w, wA[7],  tA); tB = fmaf(v1.w, wB[7],  tB);
            tA = fmaf(v2.x, wA[8],  tA); tB = fmaf(v2.x, wB[8],  tB);
            tA = fmaf(v2.y, wA[9],  tA); tB = fmaf(v2.y, wB[9],  tB);
            tA = fmaf(v2.z, wA[10], tA); tB = fmaf(v2.z, wB[10], tB);
            tA = fmaf(v2.w, wA[11], tA); tB = fmaf(v2.w, wB[11], tB);
            tA = fmaf(v3.x, wA[12], tA); tB = fmaf(v3.x, wB[12], tB);
            tA = fmaf(v3.y, wA[13], tA); tB = fmaf(v3.y, wB[13], tB);
            tA = fmaf(v3.z, wA[14], tA); tB = fmaf(v3.z, wB[14], tB);
            tA = fmaf(v3.w, wA[15], tA); tB = fmaf(v3.w, wB[15], tB);
            accA += fmaxf(tA, 0.f);
            accB += fmaxf(tB, 0.f);
        }
    }
    for (; i < end; ++i) {
        int s0 = csr_src[i];
        float qA0 = Q[(size_t)s0 * HD + lane];
        float qB0 = Q[(size_t)s0 * HD + 64 + lane];
        const float4* Ev = PERM ? (const float4*)&EA[(size_t)i * 16]
                                : (const float4*)&EA[(size_t)csr_eid[i] * 16];
        float4 v0 = Ev[0], v1 = Ev[1], v2 = Ev[2], v3 = Ev[3];
        float tA = pA + qA0, tB = pB + qB0;
        tA = fmaf(v0.x, wA[0],  tA); tB = fmaf(v0.x, wB[0],  tB);
        tA = fmaf(v0.y, wA[1],  tA); tB = fmaf(v0.y, wB[1],  tB);
        tA = fmaf(v0.z, wA[2],  tA); tB = fmaf(v0.z, wB[2],  tB);
        tA = fmaf(v0.w, wA[3],  tA); tB = fmaf(v0.w, wB[3],  tB);
        tA = fmaf(v1.x, wA[4],  tA); tB = fmaf(v1.x, wB[4],  tB);
        tA = fmaf(v1.y, wA[5],  tA); tB = fmaf(v1.y, wB[5],  tB);
        tA = fmaf(v1.z, wA[6],  tA); tB = fmaf(v1.z, wB[6],  tB);
        tA = fmaf(v1.w, wA[7],  tA); tB = fmaf(v1.w, wB[7],  tB);
        tA = fmaf(v2.x, wA[8],  tA); tB = fmaf(v2.x, wB[8],  tB);
        tA = fmaf(v2.y, wA[9],  tA); tB = fmaf(v2.y, wB[9],  tB);
        tA = fmaf(v2.z, wA[10], tA); tB = fmaf(v2.z, wB[10], tB);
        tA = fmaf(v2.w, wA[11], tA); tB = fmaf(v2.w, wB[11], tB);
        tA = fmaf(v3.x, wA[12], tA); tB = fmaf(v3.x, wB[12], tB);
        tA = fmaf(v3.y, wA[13], tA); tB = fmaf(v3.y, wB[13], tB);
        tA = fmaf(v3.z, wA[14], tA); tB = fmaf(v3.z, wB[14], tB);
        tA = fmaf(v3.w, wA[15], tA); tB = fmaf(v3.w, wB[15], tB);
        accA += fmaxf(tA, 0.f);
        accB += fmaxf(tB, 0.f);
    }
    size_t oA = (size_t)node * HD + lane;
    size_t oB = oA + 64;
    unsigned short hA = f2bf(accA);
    unsigned short hB = f2bf(accB);
    Sh[oA] = hA; Sl[oA] = f2bf(accA - bf2f(hA));
    Sh[oB] = hB; Sl[oB] = f2bf(accB - bf2f(hB));
}

// ---------------------------------------------------------------------------
// Pool (segment mean/max over sorted batch) from bf16 hi/lo h; then classifier.
// ---------------------------------------------------------------------------
__global__ __launch_bounds__(256) void k_pool2(
    const unsigned short* __restrict__ hh, const unsigned short* __restrict__ hl,
    const int* __restrict__ batch,
    float* __restrict__ gsum, unsigned int* __restrict__ gmax, int N)
{
    int nchunk = (N + gridDim.x - 1) / gridDim.x;
    int n0 = blockIdx.x * nchunk;
    int n1 = n0 + nchunk; if (n1 > N) n1 = N;
    int j = threadIdx.x & 127;
    int half = threadIdx.x >> 7;
    float s = 0.f, m = 0.f; int gcur = -1;
    for (int n = n0 + half; n < n1; n += 2) {
        int g = batch[n];
        if (g != gcur) {
            if (gcur >= 0) {
                atomicAdd(&gsum[(size_t)gcur * HD + j], s);
                atomicMax(&gmax[(size_t)gcur * HD + j], __float_as_uint(m));
            }
            gcur = g; s = 0.f; m = 0.f;
        }
        size_t o = (size_t)n * HD + j;
        float v = bf2f(hh[o]) + bf2f(hl[o]);
        s += v; m = fmaxf(m, v);
    }
    if (gcur >= 0) {
        atomicAdd(&gsum[(size_t)gcur * HD + j], s);
        atomicMax(&gmax[(size_t)gcur * HD + j], __float_as_uint(m));
    }
}

__global__ __launch_bounds__(128) void k_cls(
    const float* __restrict__ gsum, const float* __restrict__ gmax,
    const int* __restrict__ gcnt,
    const float* __restrict__ W1, const float* __restrict__ b1,
    const float* __restrict__ W2, const float* __restrict__ b2,
    const float* __restrict__ W3, const float* __restrict__ b3,
    float* __restrict__ out)
{
    __shared__ float rep[256];
    __shared__ float z1[128];
    __shared__ float z2[64];
    const int g = blockIdx.x;
    const int j = threadIdx.x;
    float cntf = (float)gcnt[g];
    rep[j]       = gsum[(size_t)g * HD + j] / fmaxf(cntf, 1.f);
    rep[128 + j] = gmax[(size_t)g * HD + j];
    __syncthreads();
    float a = 0.f;
    for (int k = 0; k < 256; ++k) a = fmaf(rep[k], W1[(size_t)k * 128 + j], a);
    z1[j] = fmaxf(a + b1[j], 0.f);
    __syncthreads();
    if (j < 64) {
        float b = 0.f;
        for (int k = 0; k < 128; ++k) b = fmaf(z1[k], W2[(size_t)k * 64 + j], b);
        z2[j] = fmaxf(b + b2[j], 0.f);
    }
    __syncthreads();
    if (j < 2) {
        float c = 0.f;
        for (int k = 0; k < 64; ++k) c = fmaf(z2[k], W3[(size_t)k * 2 + j], c);
        out[(size_t)g * 2 + j] = c + b3[j];
    }
}

extern "C" void kernel_launch(void* const* d_in, const int* in_sizes, int n_in,
                              void* d_out, int out_size, void* d_ws, size_t ws_size,
                              hipStream_t stream) {
    const float* x      = (const float*)d_in[0];
    const float* ea     = (const float*)d_in[1];
    const int*   ei     = (const int*)d_in[2];
    const int*   batch  = (const int*)d_in[3];
    const float* emb_W  = (const float*)d_in[4];
    const float* emb_b  = (const float*)d_in[5];
    const float* msg_W1 = (const float*)d_in[6];
    const float* msg_b1 = (const float*)d_in[7];
    const float* msg_W2 = (const float*)d_in[8];
    const float* msg_b2 = (const float*)d_in[9];
    const float* upd_W1 = (const float*)d_in[10];
    const float* upd_b1 = (const float*)d_in[11];
    const float* upd_W2 = (const float*)d_in[12];
    const float* upd_b2 = (const float*)d_in[13];
    const float* cW1 = (const float*)d_in[14];
    const float* cb1 = (const float*)d_in[15];
    const float* cW2 = (const float*)d_in[16];
    const float* cb2 = (const float*)d_in[17];
    const float* cW3 = (const float*)d_in[18];
    const float* cb3 = (const float*)d_in[19];

    const int N = in_sizes[0] / 64;
    const int E = in_sizes[1] / 16;
    const int G = 256, L = 3;
    const int* src = ei;
    const int* dst = ei + E;
    const int nb = (N + SCB - 1) / SCB;

    char* w = (char*)d_ws;
    size_t off = 0;
    auto alloc = [&](size_t bytes) -> void* {
        void* p = w + off;
        off += (bytes + 255) & ~(size_t)255;
        return p;
    };
    typedef unsigned short us;
    float* Pb  = (float*)alloc((size_t)N * HD * 4);  // P fp32; aliased as U pair
    float* Qb  = (float*)alloc((size_t)N * HD * 4);  // Q fp32
    us* S_h = (us*)alloc((size_t)N * HD * 2);        // S hi; aliased as x_h (N*64)
    us* S_l = (us*)alloc((size_t)N * HD * 2);        // S lo; aliased as x_l
    us* h_h = (us*)alloc((size_t)N * HD * 2);
    us* h_l = (us*)alloc((size_t)N * HD * 2);
    us* U_h = (us*)Pb;                               // alias: U pair over Pb
    us* U_l = U_h + (size_t)N * HD;
    us* x_h = S_h;                                   // alias: x pair over S pair
    us* x_l = S_l;
    float* Wcomb = (float*)alloc((size_t)L * 256 * HD * 4);
    float* bvec2 = (float*)alloc((size_t)L * HD * 4);
    us* embt_h = (us*)alloc((size_t)128 * 64 * 2);
    us* embt_l = (us*)alloc((size_t)128 * 64 * 2);
    us* Wabt_h = (us*)alloc((size_t)L * 128 * 256 * 2);
    us* Wabt_l = (us*)alloc((size_t)L * 128 * 256 * 2);
    us* Wcbt_h = (us*)alloc((size_t)L * 128 * 256 * 2);
    us* Wcbt_l = (us*)alloc((size_t)L * 128 * 256 * 2);
    us* U2t_h  = (us*)alloc((size_t)L * 128 * 128 * 2);
    us* U2t_l  = (us*)alloc((size_t)L * 128 * 128 * 2);
    int*   degi   = (int*)alloc((size_t)N * 4);
    float* degf   = (float*)alloc((size_t)N * 4);
    int*   rowptr = (int*)alloc((size_t)(N + 1) * 4);
    int*   cursor = (int*)alloc((size_t)N * 4);
    int*   thrpre = (int*)alloc((size_t)nb * 256 * 4);
    int*   bsum   = (int*)alloc((size_t)(nb + 1) * 4);
    int*   boff   = (int*)alloc((size_t)(nb + 1) * 4);
    int*   gcnt   = (int*)alloc(256 * 4);
    float* gsum   = (float*)alloc((size_t)G * HD * 4);
    float* gmax   = (float*)alloc((size_t)G * HD * 4);
    int*   csr_src = (int*)alloc((size_t)E * 4);
    int*   csr_eid = (int*)alloc((size_t)E * 4);
    float* ea_p = nullptr;
    if (ws_size && off + (size_t)E * 16 * 4 + 256 <= ws_size)
        ea_p = (float*)alloc((size_t)E * 16 * 4);
    (void)n_in; (void)out_size;

    hipMemsetAsync(degi, 0, (size_t)N * 4, stream);
    hipMemsetAsync(gcnt, 0, 256 * 4, stream);
    hipMemsetAsync(gsum, 0, (size_t)G * HD * 4, stream);
    hipMemsetAsync(gmax, 0, (size_t)G * HD * 4, stream);

    // ---- CSR build (parallel scan) ----
    k_deg<<<(E + 255) / 256, 256, 0, stream>>>(dst, degi, E);
    k_hist<<<(N + 255) / 256, 256, 0, stream>>>(batch, gcnt, N);
    k_scan1<<<nb, 256, 0, stream>>>(degi, thrpre, bsum, N);
    k_scan2<<<1, 64, 0, stream>>>(bsum, boff, nb);
    k_scan3<<<nb, 256, 0, stream>>>(degi, thrpre, boff, rowptr, cursor, degf, N, E);
    k_scatter<<<(E + 255) / 256, 256, 0, stream>>>(dst, src, cursor, csr_src, csr_eid, E);
    if (ea_p)
        k_permEA<<<(int)(((long long)E * 4 + 255) / 256), 256, 0, stream>>>(ea, csr_eid, ea_p, E);

    // ---- weight folds + conversions ----
    for (int l = 0; l < L; ++l)
        hipMemcpyAsync(Wcomb + (size_t)l * 256 * HD,
                       upd_W1 + (size_t)l * 256 * HD,
                       (size_t)HD * HD * 4, hipMemcpyDeviceToDevice, stream);
    k_foldW<<<L * 8, 256, 0, stream>>>(msg_W2, upd_W1, Wcomb);
    k_foldb<<<L, 128, 0, stream>>>(msg_b2, upd_W1, bvec2);

    k_cvtA<<<(int)(((long)N * 64 + 255) / 256), 256, 0, stream>>>(x, x_h, x_l, (long)N * 64);
    k_cvtW<<<dim3(32, 1), 256, 0, stream>>>(emb_W, 0, 64, embt_h, embt_l, 0);
    k_cvtW<<<dim3(128, L), 256, 0, stream>>>(msg_W1, 272 * 128, 256, Wabt_h, Wabt_l, 128 * 256);
    k_cvtW<<<dim3(128, L), 256, 0, stream>>>(Wcomb, 256 * 128, 256, Wcbt_h, Wcbt_l, 128 * 256);
    k_cvtW<<<dim3(64, L), 256, 0, stream>>>(upd_W2, 128 * 128, 128, U2t_h, U2t_l, 128 * 128);

    const int gb = (N + 63) / 64;
    // ---- embed: h = x @ emb_W + emb_b (no relu) -> h pair ----
    k_mgemm<2, 64, false, false, false, false, true><<<gb, 256, 0, stream>>>(
        x_h, x_l, nullptr, nullptr, 0, embt_h, embt_l, 64,
        emb_b, nullptr, nullptr, nullptr, h_h, h_l, N);

    for (int l = 0; l < L; ++l) {
        const float* W1 = msg_W1 + (size_t)l * 272 * HD;
        const us* Wat_h = Wabt_h + (size_t)l * 128 * 256;
        const us* Wat_l = Wabt_l + (size_t)l * 128 * 256;
        // P = h@Wa + b1 (fp32)
        k_mgemm<4, 128, false, false, false, true, false><<<gb, 256, 0, stream>>>(
            h_h, h_l, nullptr, nullptr, 0, Wat_h, Wat_l, 256,
            msg_b1 + (size_t)l * HD, nullptr, nullptr, Pb, nullptr, nullptr, N);
        // Q = h@Wb (fp32)
        k_mgemm<4, 128, false, false, false, true, false><<<gb, 256, 0, stream>>>(
            h_h, h_l, nullptr, nullptr, 0, Wat_h + 128, Wat_l + 128, 256,
            nullptr, nullptr, nullptr, Qb, nullptr, nullptr, N);
        // S[n] = sum_in relu(P[n] + Q[src] + ea@Wc) -> bf16 pair
        if (ea_p)
            k_edge<true><<<(N + 3) / 4, 256, 0, stream>>>(Pb, Qb, ea_p, rowptr,
                                                          csr_src, nullptr,
                                                          W1 + 256 * HD, S_h, S_l, N);
        else
            k_edge<false><<<(N + 3) / 4, 256, 0, stream>>>(Pb, Qb, ea, rowptr,
                                                           csr_src, csr_eid,
                                                           W1 + 256 * HD, S_h, S_l, N);
        // U = relu([h|S] @ Wcomb + b1u + deg*bvec2) -> U pair (overwrites Pb)
        k_mgemm<8, 128, true, true, true, false, true><<<gb, 256, 0, stream>>>(
            h_h, h_l, S_h, S_l, 128,
            Wcbt_h + (size_t)l * 128 * 256, Wcbt_l + (size_t)l * 128 * 256, 256,
            upd_b1 + (size_t)l * HD, bvec2 + (size_t)l * HD, degf,
            nullptr, U_h, U_l, N);
        // h = relu(U @ U2 + b2u) -> h pair
        k_mgemm<4, 128, false, true, false, false, true><<<gb, 256, 0, stream>>>(
            U_h, U_l, nullptr, nullptr, 0,
            U2t_h + (size_t)l * 128 * 128, U2t_l + (size_t)l * 128 * 128, 128,
            upd_b2 + (size_t)l * HD, nullptr, nullptr, nullptr, h_h, h_l, N);
    }

    k_pool2<<<1024, 256, 0, stream>>>(h_h, h_l, batch, gsum, (unsigned int*)gmax, N);
    k_cls<<<G, 128, 0, stream>>>(gsum, gmax, gcnt, cW1, cb1, cW2, cb2, cW3, cb3,
                                 (float*)d_out);
}

// Round 6
// 1163.422 us; speedup vs baseline: 1.0276x; 1.0276x over previous
//
#include <hip/hip_runtime.h>
#include <hip/hip_bf16.h>

#define HD 128
#define SCB 2048   // elements per scan block

typedef __attribute__((ext_vector_type(8))) short short8v;
typedef __attribute__((ext_vector_type(4))) float f32x4;
typedef unsigned short us;

__device__ __forceinline__ us f2bf(float f) {
    union { float f; unsigned u; } c; c.f = f;
    unsigned u = c.u;
    return (us)((u + 0x7fffu + ((u >> 16) & 1u)) >> 16);
}
__device__ __forceinline__ float bf2f(us b) {
    union { unsigned u; float f; } c; c.u = ((unsigned)b) << 16;
    return c.f;
}

// ---------------------------------------------------------------------------
// MFMA node GEMM, fp32 via bf16 hi/lo split (3 MFMA per logical fp32 MFMA).
// Wave tile: 64 rows x 16 cols -> the ENTIRE K-extent of B (hi+lo) lives in
// registers (KSTEPS*2 short8v), loaded once. K-loop only streams A.
// A = [A1|A2] hi/lo pairs row-major. Wt[j][k] hi/lo, ldw = KSTEPS*32.
// Grid: x = ceil(nrows/64), y = NCOLS/64; block 256 (4 waves = 64 cols).
// Frag maps (HW-verified in round 5): A row=lane&15, k=(lane>>4)*8+i;
// B col=lane&15, same k; D col=lane&15, row=(lane>>4)*4+reg.
// ---------------------------------------------------------------------------
template<int KSTEPS, int K1, bool HASA2, bool RELU, bool DEGB, bool WF32, bool WBF>
__global__ __launch_bounds__(256) void k_mgemm(
    const us* __restrict__ A1h, const us* __restrict__ A1l,
    const us* __restrict__ A2h, const us* __restrict__ A2l, int K2,
    const us* __restrict__ Wth, const us* __restrict__ Wtl,
    const float* __restrict__ bias,
    const float* __restrict__ bdeg, const float* __restrict__ deg,
    float* __restrict__ Cf0, float* __restrict__ Cf1,
    us* __restrict__ Ch, us* __restrict__ Cl,
    int nrows)
{
    const int tid  = threadIdx.x;
    const int wv   = tid >> 6;
    const int lane = tid & 63;
    const int r    = lane & 15;
    const int g    = lane >> 4;
    const int rb   = blockIdx.x * 64;
    const int col  = blockIdx.y * 64 + wv * 16 + r;
    const int KT   = KSTEPS * 32;

    // B fragments for the whole K in registers (loaded once, L2-hit)
    short8v bh[KSTEPS], bl[KSTEPS];
    {
        size_t wbase = (size_t)col * KT + (size_t)(g * 8);
#pragma unroll
        for (int s = 0; s < KSTEPS; ++s) {
            bh[s] = *(const short8v*)(Wth + wbase + s * 32);
            bl[s] = *(const short8v*)(Wtl + wbase + s * 32);
        }
    }

    f32x4 acc[4];
#pragma unroll
    for (int t = 0; t < 4; ++t) acc[t] = (f32x4){0.f, 0.f, 0.f, 0.f};

    int arow[4];
#pragma unroll
    for (int t = 0; t < 4; ++t) {
        int rr = rb + t * 16 + r;
        arow[t] = (rr < nrows) ? rr : (nrows - 1);
    }

#pragma unroll
    for (int s = 0; s < KSTEPS; ++s) {
        const int k0 = s * 32;
        short8v ah[4], al[4];
#pragma unroll
        for (int t = 0; t < 4; ++t) {
            if (!HASA2 || k0 < K1) {
                size_t o = (size_t)arow[t] * K1 + (size_t)(k0 + g * 8);
                ah[t] = *(const short8v*)(A1h + o);
                al[t] = *(const short8v*)(A1l + o);
            } else {
                size_t o = (size_t)arow[t] * K2 + (size_t)(k0 - K1 + g * 8);
                ah[t] = *(const short8v*)(A2h + o);
                al[t] = *(const short8v*)(A2l + o);
            }
        }
#pragma unroll
        for (int t = 0; t < 4; ++t) {
            acc[t] = __builtin_amdgcn_mfma_f32_16x16x32_bf16(ah[t], bh[s], acc[t], 0, 0, 0);
            acc[t] = __builtin_amdgcn_mfma_f32_16x16x32_bf16(al[t], bh[s], acc[t], 0, 0, 0);
            acc[t] = __builtin_amdgcn_mfma_f32_16x16x32_bf16(ah[t], bl[s], acc[t], 0, 0, 0);
        }
    }

    const float bb = (bias && col < 128) ? bias[col] : 0.f;
    const float bd = (DEGB && col < 128) ? bdeg[col] : 0.f;
    const int jc = col & 127;
#pragma unroll
    for (int t = 0; t < 4; ++t) {
#pragma unroll
        for (int i = 0; i < 4; ++i) {
            int row = rb + t * 16 + g * 4 + i;
            if (row >= nrows) continue;
            float v = acc[t][i] + bb;
            if (DEGB) v += deg[row] * bd;
            if (RELU) v = fmaxf(v, 0.f);
            size_t o = (size_t)row * HD + jc;
            if (WF32) (col < 128 ? Cf0 : Cf1)[o] = v;
            if (WBF) {
                us hh = f2bf(v);
                Ch[o] = hh;
                Cl[o] = f2bf(v - bf2f(hh));
            }
        }
    }
}

// ---------------------------------------------------------------------------
// Conversions
// ---------------------------------------------------------------------------
__global__ void k_cvtA(const float* __restrict__ src,
                       us* __restrict__ dh, us* __restrict__ dl, long n)
{
    long i = (long)blockIdx.x * blockDim.x + threadIdx.x;
    if (i >= n) return;
    float v = src[i];
    us h = f2bf(v);
    dh[i] = h;
    dl[i] = f2bf(v - bf2f(h));
}

// transpose [K][128] fp32 -> [128 j][K] bf16 hi/lo (per layer via blockIdx.y)
__global__ void k_cvtW(const float* __restrict__ src, long sstride, int K,
                       us* __restrict__ dh, us* __restrict__ dl, long dstride)
{
    int l = blockIdx.y;
    int idx = blockIdx.x * 256 + threadIdx.x;
    if (idx >= K * 128) return;
    int k = idx >> 7, j = idx & 127;
    float v = src[(size_t)l * sstride + (size_t)k * 128 + j];
    us h = f2bf(v);
    size_t o = (size_t)l * dstride + (size_t)j * K + k;
    dh[o] = h;
    dl[o] = f2bf(v - bf2f(h));
}

// ---------------------------------------------------------------------------
// CSR build: deg -> 3-phase parallel scan -> scatter
// ---------------------------------------------------------------------------
__global__ void k_deg(const int* __restrict__ dst, int* __restrict__ degi, int E)
{
    int e = blockIdx.x * blockDim.x + threadIdx.x;
    if (e < E) atomicAdd(&degi[dst[e]], 1);
}

__global__ void k_hist(const int* __restrict__ batch, int* __restrict__ gcnt, int N)
{
    int n = blockIdx.x * blockDim.x + threadIdx.x;
    if (n < N) atomicAdd(&gcnt[batch[n]], 1);
}

__global__ __launch_bounds__(256) void k_scan1(const int* __restrict__ degi,
                                               int* __restrict__ thrpre,
                                               int* __restrict__ bsum, int N)
{
    __shared__ int sc[256];
    const int t = threadIdx.x, b = blockIdx.x;
    int i0 = b * SCB + t * 8;
    int s = 0;
#pragma unroll
    for (int q = 0; q < 8; ++q) {
        int i = i0 + q;
        if (i < N) s += degi[i];
    }
    sc[t] = s;
    __syncthreads();
    for (int o = 1; o < 256; o <<= 1) {
        int v = (t >= o) ? sc[t - o] : 0;
        __syncthreads();
        sc[t] += v;
        __syncthreads();
    }
    thrpre[b * 256 + t] = sc[t] - s;
    if (t == 255) bsum[b] = sc[255];
}

__global__ void k_scan2(const int* __restrict__ bsum, int* __restrict__ boff, int nb)
{
    if (threadIdx.x == 0 && blockIdx.x == 0) {
        int run = 0;
        for (int b = 0; b < nb; ++b) { boff[b] = run; run += bsum[b]; }
    }
}

__global__ __launch_bounds__(256) void k_scan3(
    const int* __restrict__ degi, const int* __restrict__ thrpre,
    const int* __restrict__ boff,
    int* __restrict__ rowptr, int* __restrict__ cursor,
    float* __restrict__ degf, int N, int E)
{
    const int t = threadIdx.x, b = blockIdx.x;
    int run = boff[b] + thrpre[b * 256 + t];
    int i0 = b * SCB + t * 8;
#pragma unroll
    for (int q = 0; q < 8; ++q) {
        int i = i0 + q;
        if (i < N) {
            int d = degi[i];
            rowptr[i] = run;
            cursor[i] = run;
            degf[i] = (float)d;
            run += d;
        }
    }
    if (b == 0 && t == 0) rowptr[N] = E;
}

__global__ void k_scatter(const int* __restrict__ dst, const int* __restrict__ src,
                          int* __restrict__ cursor,
                          int* __restrict__ csr_src, int* __restrict__ csr_eid, int E)
{
    int e = blockIdx.x * blockDim.x + threadIdx.x;
    if (e < E) {
        int d = dst[e];
        int pos = atomicAdd(&cursor[d], 1);
        csr_src[pos] = src[e];
        csr_eid[pos] = e;
    }
}

__global__ void k_permEA(const float* __restrict__ ea, const int* __restrict__ csr_eid,
                         float* __restrict__ ea_p, int E)
{
    long long gid = (long long)blockIdx.x * blockDim.x + threadIdx.x;
    if (gid >= (long long)E * 4) return;
    int pos = (int)(gid >> 2), part = (int)(gid & 3);
    int e = csr_eid[pos];
    ((float4*)ea_p)[(size_t)pos * 4 + part] = ((const float4*)ea)[(size_t)e * 4 + part];
}

// ---------------------------------------------------------------------------
// Weight folds: Wcomb rows 128..255 = W2 @ U1b ; bvec2 = b2 @ U1b
// ---------------------------------------------------------------------------
__global__ __launch_bounds__(256) void k_foldW(
    const float* __restrict__ msg_W2, const float* __restrict__ upd_W1,
    float* __restrict__ Wcomb)
{
    int l = blockIdx.x >> 3, rb = blockIdx.x & 7;
    const float* W2  = msg_W2 + (size_t)l * HD * HD;
    const float* U1b = upd_W1 + (size_t)l * 256 * HD + (size_t)HD * HD;
    float* Wout = Wcomb + (size_t)l * 256 * HD + (size_t)HD * HD;
    int j = threadIdx.x & 127;
    int rh = threadIdx.x >> 7;
    int r0 = rb * 16 + rh * 8;
    float acc[8] = {0.f,0.f,0.f,0.f,0.f,0.f,0.f,0.f};
    for (int k = 0; k < HD; ++k) {
        float u = U1b[(size_t)k * HD + j];
#pragma unroll
        for (int rr = 0; rr < 8; ++rr)
            acc[rr] = fmaf(W2[(size_t)(r0 + rr) * HD + k], u, acc[rr]);
    }
#pragma unroll
    for (int rr = 0; rr < 8; ++rr)
        Wout[(size_t)(r0 + rr) * HD + j] = acc[rr];
}

__global__ __launch_bounds__(128) void k_foldb(
    const float* __restrict__ msg_b2, const float* __restrict__ upd_W1,
    float* __restrict__ bvec2)
{
    int l = blockIdx.x, j = threadIdx.x;
    const float* U1b = upd_W1 + (size_t)l * 256 * HD + (size_t)HD * HD;
    const float* b2 = msg_b2 + (size_t)l * HD;
    float acc = 0.f;
    for (int k = 0; k < HD; ++k) acc = fmaf(b2[k], U1b[(size_t)k * HD + j], acc);
    bvec2[(size_t)l * HD + j] = acc;
}

// ---------------------------------------------------------------------------
// Edge gather: S[n] = sum_{e:dst=n} relu(P[n] + Q[src] + ea@Wc)
// wave per node; 4-edge unroll. Output written as bf16 hi/lo pair.
// ---------------------------------------------------------------------------
template<bool PERM>
__global__ __launch_bounds__(256) void k_edge(
    const float* __restrict__ P, const float* __restrict__ Q,
    const float* __restrict__ EA,
    const int* __restrict__ rowptr,
    const int* __restrict__ csr_src, const int* __restrict__ csr_eid,
    const float* __restrict__ W1c,
    us* __restrict__ Sh, us* __restrict__ Sl, int N)
{
    const int lane = threadIdx.x & 63;
    const int node = blockIdx.x * 4 + (threadIdx.x >> 6);
    if (node >= N) return;
    float wA[16], wB[16];
#pragma unroll
    for (int k = 0; k < 16; ++k) {
        wA[k] = W1c[k * HD + lane];
        wB[k] = W1c[k * HD + 64 + lane];
    }
    const int beg = rowptr[node], end = rowptr[node + 1];
    const float pA = P[(size_t)node * HD + lane];
    const float pB = P[(size_t)node * HD + 64 + lane];
    float accA = 0.f, accB = 0.f;

    int i = beg;
    for (; i + 4 <= end; i += 4) {
        int s[4];
        s[0] = csr_src[i]; s[1] = csr_src[i + 1];
        s[2] = csr_src[i + 2]; s[3] = csr_src[i + 3];
        float qA[4], qB[4];
#pragma unroll
        for (int r2 = 0; r2 < 4; ++r2) {
            qA[r2] = Q[(size_t)s[r2] * HD + lane];
            qB[r2] = Q[(size_t)s[r2] * HD + 64 + lane];
        }
#pragma unroll
        for (int r2 = 0; r2 < 4; ++r2) {
            const float4* Ev = PERM ? (const float4*)&EA[(size_t)(i + r2) * 16]
                                    : (const float4*)&EA[(size_t)csr_eid[i + r2] * 16];
            float4 v0 = Ev[0], v1 = Ev[1], v2 = Ev[2], v3 = Ev[3];
            float tA = pA + qA[r2], tB = pB + qB[r2];
            tA = fmaf(v0.x, wA[0],  tA); tB = fmaf(v0.x, wB[0],  tB);
            tA = fmaf(v0.y, wA[1],  tA); tB = fmaf(v0.y, wB[1],  tB);
            tA = fmaf(v0.z, wA[2],  tA); tB = fmaf(v0.z, wB[2],  tB);
            tA = fmaf(v0.w, wA[3],  tA); tB = fmaf(v0.w, wB[3],  tB);
            tA = fmaf(v1.x, wA[4],  tA); tB = fmaf(v1.x, wB[4],  tB);
            tA = fmaf(v1.y, wA[5],  tA); tB = fmaf(v1.y, wB[5],  tB);
            tA = fmaf(v1.z, wA[6],  tA); tB = fmaf(v1.z, wB[6],  tB);
            tA = fmaf(v1.w, wA[7],  tA); tB = fmaf(v1.w, wB[7],  tB);
            tA = fmaf(v2.x, wA[8],  tA); tB = fmaf(v2.x, wB[8],  tB);
            tA = fmaf(v2.y, wA[9],  tA); tB = fmaf(v2.y, wB[9],  tB);
            tA = fmaf(v2.z, wA[10], tA); tB = fmaf(v2.z, wB[10], tB);
            tA = fmaf(v2.w, wA[11], tA); tB = fmaf(v2.w, wB[11], tB);
            tA = fmaf(v3.x, wA[12], tA); tB = fmaf(v3.x, wB[12], tB);
            tA = fmaf(v3.y, wA[13], tA); tB = fmaf(v3.y, wB[13], tB);
            tA = fmaf(v3.z, wA[14], tA); tB = fmaf(v3.z, wB[14], tB);
            tA = fmaf(v3.w, wA[15], tA); tB = fmaf(v3.w, wB[15], tB);
            accA += fmaxf(tA, 0.f);
            accB += fmaxf(tB, 0.f);
        }
    }
    for (; i < end; ++i) {
        int s0 = csr_src[i];
        float qA0 = Q[(size_t)s0 * HD + lane];
        float qB0 = Q[(size_t)s0 * HD + 64 + lane];
        const float4* Ev = PERM ? (const float4*)&EA[(size_t)i * 16]
                                : (const float4*)&EA[(size_t)csr_eid[i] * 16];
        float4 v0 = Ev[0], v1 = Ev[1], v2 = Ev[2], v3 = Ev[3];
        float tA = pA + qA0, tB = pB + qB0;
        tA = fmaf(v0.x, wA[0],  tA); tB = fmaf(v0.x, wB[0],  tB);
        tA = fmaf(v0.y, wA[1],  tA); tB = fmaf(v0.y, wB[1],  tB);
        tA = fmaf(v0.z, wA[2],  tA); tB = fmaf(v0.z, wB[2],  tB);
        tA = fmaf(v0.w, wA[3],  tA); tB = fmaf(v0.w, wB[3],  tB);
        tA = fmaf(v1.x, wA[4],  tA); tB = fmaf(v1.x, wB[4],  tB);
        tA = fmaf(v1.y, wA[5],  tA); tB = fmaf(v1.y, wB[5],  tB);
        tA = fmaf(v1.z, wA[6],  tA); tB = fmaf(v1.z, wB[6],  tB);
        tA = fmaf(v1.w, wA[7],  tA); tB = fmaf(v1.w, wB[7],  tB);
        tA = fmaf(v2.x, wA[8],  tA); tB = fmaf(v2.x, wB[8],  tB);
        tA = fmaf(v2.y, wA[9],  tA); tB = fmaf(v2.y, wB[9],  tB);
        tA = fmaf(v2.z, wA[10], tA); tB = fmaf(v2.z, wB[10], tB);
        tA = fmaf(v2.w, wA[11], tA); tB = fmaf(v2.w, wB[11], tB);
        tA = fmaf(v3.x, wA[12], tA); tB = fmaf(v3.x, wB[12], tB);
        tA = fmaf(v3.y, wA[13], tA); tB = fmaf(v3.y, wB[13], tB);
        tA = fmaf(v3.z, wA[14], tA); tB = fmaf(v3.z, wB[14], tB);
        tA = fmaf(v3.w, wA[15], tA); tB = fmaf(v3.w, wB[15], tB);
        accA += fmaxf(tA, 0.f);
        accB += fmaxf(tB, 0.f);
    }
    size_t oA = (size_t)node * HD + lane;
    size_t oB = oA + 64;
    us hA = f2bf(accA);
    us hB = f2bf(accB);
    Sh[oA] = hA; Sl[oA] = f2bf(accA - bf2f(hA));
    Sh[oB] = hB; Sl[oB] = f2bf(accB - bf2f(hB));
}

// ---------------------------------------------------------------------------
// Pool (segment mean/max over sorted batch) from bf16 hi/lo h; then classifier.
// ---------------------------------------------------------------------------
__global__ __launch_bounds__(256) void k_pool2(
    const us* __restrict__ hh, const us* __restrict__ hl,
    const int* __restrict__ batch,
    float* __restrict__ gsum, unsigned int* __restrict__ gmax, int N)
{
    int nchunk = (N + gridDim.x - 1) / gridDim.x;
    int n0 = blockIdx.x * nchunk;
    int n1 = n0 + nchunk; if (n1 > N) n1 = N;
    int j = threadIdx.x & 127;
    int half = threadIdx.x >> 7;
    float s = 0.f, m = 0.f; int gcur = -1;
    for (int n = n0 + half; n < n1; n += 2) {
        int g = batch[n];
        if (g != gcur) {
            if (gcur >= 0) {
                atomicAdd(&gsum[(size_t)gcur * HD + j], s);
                atomicMax(&gmax[(size_t)gcur * HD + j], __float_as_uint(m));
            }
            gcur = g; s = 0.f; m = 0.f;
        }
        size_t o = (size_t)n * HD + j;
        float v = bf2f(hh[o]) + bf2f(hl[o]);
        s += v; m = fmaxf(m, v);
    }
    if (gcur >= 0) {
        atomicAdd(&gsum[(size_t)gcur * HD + j], s);
        atomicMax(&gmax[(size_t)gcur * HD + j], __float_as_uint(m));
    }
}

__global__ __launch_bounds__(128) void k_cls(
    const float* __restrict__ gsum, const float* __restrict__ gmax,
    const int* __restrict__ gcnt,
    const float* __restrict__ W1, const float* __restrict__ b1,
    const float* __restrict__ W2, const float* __restrict__ b2,
    const float* __restrict__ W3, const float* __restrict__ b3,
    float* __restrict__ out)
{
    __shared__ float rep[256];
    __shared__ float z1[128];
    __shared__ float z2[64];
    const int g = blockIdx.x;
    const int j = threadIdx.x;
    float cntf = (float)gcnt[g];
    rep[j]       = gsum[(size_t)g * HD + j] / fmaxf(cntf, 1.f);
    rep[128 + j] = gmax[(size_t)g * HD + j];
    __syncthreads();
    float a = 0.f;
    for (int k = 0; k < 256; ++k) a = fmaf(rep[k], W1[(size_t)k * 128 + j], a);
    z1[j] = fmaxf(a + b1[j], 0.f);
    __syncthreads();
    if (j < 64) {
        float b = 0.f;
        for (int k = 0; k < 128; ++k) b = fmaf(z1[k], W2[(size_t)k * 64 + j], b);
        z2[j] = fmaxf(b + b2[j], 0.f);
    }
    __syncthreads();
    if (j < 2) {
        float c = 0.f;
        for (int k = 0; k < 64; ++k) c = fmaf(z2[k], W3[(size_t)k * 2 + j], c);
        out[(size_t)g * 2 + j] = c + b3[j];
    }
}

extern "C" void kernel_launch(void* const* d_in, const int* in_sizes, int n_in,
                              void* d_out, int out_size, void* d_ws, size_t ws_size,
                              hipStream_t stream) {
    const float* x      = (const float*)d_in[0];
    const float* ea     = (const float*)d_in[1];
    const int*   ei     = (const int*)d_in[2];
    const int*   batch  = (const int*)d_in[3];
    const float* emb_W  = (const float*)d_in[4];
    const float* emb_b  = (const float*)d_in[5];
    const float* msg_W1 = (const float*)d_in[6];
    const float* msg_b1 = (const float*)d_in[7];
    const float* msg_W2 = (const float*)d_in[8];
    const float* msg_b2 = (const float*)d_in[9];
    const float* upd_W1 = (const float*)d_in[10];
    const float* upd_b1 = (const float*)d_in[11];
    const float* upd_W2 = (const float*)d_in[12];
    const float* upd_b2 = (const float*)d_in[13];
    const float* cW1 = (const float*)d_in[14];
    const float* cb1 = (const float*)d_in[15];
    const float* cW2 = (const float*)d_in[16];
    const float* cb2 = (const float*)d_in[17];
    const float* cW3 = (const float*)d_in[18];
    const float* cb3 = (const float*)d_in[19];

    const int N = in_sizes[0] / 64;
    const int E = in_sizes[1] / 16;
    const int G = 256, L = 3;
    const int* src = ei;
    const int* dst = ei + E;
    const int nb = (N + SCB - 1) / SCB;

    char* w = (char*)d_ws;
    size_t off = 0;
    auto alloc = [&](size_t bytes) -> void* {
        void* p = w + off;
        off += (bytes + 255) & ~(size_t)255;
        return p;
    };
    float* Pb  = (float*)alloc((size_t)N * HD * 4);  // P fp32; aliased as U pair
    float* Qb  = (float*)alloc((size_t)N * HD * 4);  // Q fp32
    us* S_h = (us*)alloc((size_t)N * HD * 2);        // S hi; aliased as x_h
    us* S_l = (us*)alloc((size_t)N * HD * 2);        // S lo; aliased as x_l
    us* h_h = (us*)alloc((size_t)N * HD * 2);
    us* h_l = (us*)alloc((size_t)N * HD * 2);
    us* U_h = (us*)Pb;                               // alias: U pair over Pb
    us* U_l = U_h + (size_t)N * HD;
    us* x_h = S_h;                                   // alias: x pair over S pair
    us* x_l = S_l;
    float* Wcomb = (float*)alloc((size_t)L * 256 * HD * 4);
    float* bvec2 = (float*)alloc((size_t)L * HD * 4);
    us* embt_h = (us*)alloc((size_t)128 * 64 * 2);
    us* embt_l = (us*)alloc((size_t)128 * 64 * 2);
    us* WPQt_h = (us*)alloc((size_t)L * 256 * 128 * 2);  // [256 j][128 k]
    us* WPQt_l = (us*)alloc((size_t)L * 256 * 128 * 2);
    us* Wcbt_h = (us*)alloc((size_t)L * 128 * 256 * 2);  // [128 j][256 k]
    us* Wcbt_l = (us*)alloc((size_t)L * 128 * 256 * 2);
    us* U2t_h  = (us*)alloc((size_t)L * 128 * 128 * 2);
    us* U2t_l  = (us*)alloc((size_t)L * 128 * 128 * 2);
    int*   degi   = (int*)alloc((size_t)N * 4);
    float* degf   = (float*)alloc((size_t)N * 4);
    int*   rowptr = (int*)alloc((size_t)(N + 1) * 4);
    int*   cursor = (int*)alloc((size_t)N * 4);
    int*   thrpre = (int*)alloc((size_t)nb * 256 * 4);
    int*   bsum   = (int*)alloc((size_t)(nb + 1) * 4);
    int*   boff   = (int*)alloc((size_t)(nb + 1) * 4);
    int*   gcnt   = (int*)alloc(256 * 4);
    float* gsum   = (float*)alloc((size_t)G * HD * 4);
    float* gmax   = (float*)alloc((size_t)G * HD * 4);
    int*   csr_src = (int*)alloc((size_t)E * 4);
    int*   csr_eid = (int*)alloc((size_t)E * 4);
    float* ea_p = nullptr;
    if (ws_size && off + (size_t)E * 16 * 4 + 256 <= ws_size)
        ea_p = (float*)alloc((size_t)E * 16 * 4);
    (void)n_in; (void)out_size;

    hipMemsetAsync(degi, 0, (size_t)N * 4, stream);
    hipMemsetAsync(gcnt, 0, 256 * 4, stream);
    hipMemsetAsync(gsum, 0, (size_t)G * HD * 4, stream);
    hipMemsetAsync(gmax, 0, (size_t)G * HD * 4, stream);

    // ---- CSR build (parallel scan) ----
    k_deg<<<(E + 255) / 256, 256, 0, stream>>>(dst, degi, E);
    k_hist<<<(N + 255) / 256, 256, 0, stream>>>(batch, gcnt, N);
    k_scan1<<<nb, 256, 0, stream>>>(degi, thrpre, bsum, N);
    k_scan2<<<1, 64, 0, stream>>>(bsum, boff, nb);
    k_scan3<<<nb, 256, 0, stream>>>(degi, thrpre, boff, rowptr, cursor, degf, N, E);
    k_scatter<<<(E + 255) / 256, 256, 0, stream>>>(dst, src, cursor, csr_src, csr_eid, E);
    if (ea_p)
        k_permEA<<<(int)(((long long)E * 4 + 255) / 256), 256, 0, stream>>>(ea, csr_eid, ea_p, E);

    // ---- weight folds + conversions ----
    for (int l = 0; l < L; ++l)
        hipMemcpyAsync(Wcomb + (size_t)l * 256 * HD,
                       upd_W1 + (size_t)l * 256 * HD,
                       (size_t)HD * HD * 4, hipMemcpyDeviceToDevice, stream);
    k_foldW<<<L * 8, 256, 0, stream>>>(msg_W2, upd_W1, Wcomb);
    k_foldb<<<L, 128, 0, stream>>>(msg_b2, upd_W1, bvec2);

    k_cvtA<<<(int)(((long)N * 64 + 255) / 256), 256, 0, stream>>>(x, x_h, x_l, (long)N * 64);
    k_cvtW<<<dim3(32, 1), 256, 0, stream>>>(emb_W, 0, 64, embt_h, embt_l, 0);
    // [Wa|Wb] -> WPQt [256 j][128 k]: Wa into j<128, Wb into j>=128
    k_cvtW<<<dim3(64, L), 256, 0, stream>>>(msg_W1, 272 * 128, 128,
                                            WPQt_h, WPQt_l, 256 * 128);
    k_cvtW<<<dim3(64, L), 256, 0, stream>>>(msg_W1 + 128 * 128, 272 * 128, 128,
                                            WPQt_h + 128 * 128, WPQt_l + 128 * 128,
                                            256 * 128);
    k_cvtW<<<dim3(128, L), 256, 0, stream>>>(Wcomb, 256 * 128, 256,
                                             Wcbt_h, Wcbt_l, 128 * 256);
    k_cvtW<<<dim3(64, L), 256, 0, stream>>>(upd_W2, 128 * 128, 128,
                                            U2t_h, U2t_l, 128 * 128);

    const int gb = (N + 63) / 64;
    // ---- embed: h = x @ emb_W + emb_b (no relu) -> h pair ----
    k_mgemm<2, 64, false, false, false, false, true><<<dim3(gb, 2), 256, 0, stream>>>(
        x_h, x_l, nullptr, nullptr, 0, embt_h, embt_l,
        emb_b, nullptr, nullptr, nullptr, nullptr, h_h, h_l, N);

    for (int l = 0; l < L; ++l) {
        const float* W1 = msg_W1 + (size_t)l * 272 * HD;
        // [P|Q] = h @ [Wa|Wb] (+b1 on P cols) -> Pb, Qb fp32, one dispatch
        k_mgemm<4, 128, false, false, false, true, false><<<dim3(gb, 4), 256, 0, stream>>>(
            h_h, h_l, nullptr, nullptr, 0,
            WPQt_h + (size_t)l * 256 * 128, WPQt_l + (size_t)l * 256 * 128,
            msg_b1 + (size_t)l * HD, nullptr, nullptr, Pb, Qb, nullptr, nullptr, N);
        // S[n] = sum_in relu(P[n] + Q[src] + ea@Wc) -> bf16 pair
        if (ea_p)
            k_edge<true><<<(N + 3) / 4, 256, 0, stream>>>(Pb, Qb, ea_p, rowptr,
                                                          csr_src, nullptr,
                                                          W1 + 256 * HD, S_h, S_l, N);
        else
            k_edge<false><<<(N + 3) / 4, 256, 0, stream>>>(Pb, Qb, ea, rowptr,
                                                           csr_src, csr_eid,
                                                           W1 + 256 * HD, S_h, S_l, N);
        // U = relu([h|S] @ Wcomb + b1u + deg*bvec2) -> U pair (overwrites Pb)
        k_mgemm<8, 128, true, true, true, false, true><<<dim3(gb, 2), 256, 0, stream>>>(
            h_h, h_l, S_h, S_l, 128,
            Wcbt_h + (size_t)l * 128 * 256, Wcbt_l + (size_t)l * 128 * 256,
            upd_b1 + (size_t)l * HD, bvec2 + (size_t)l * HD, degf,
            nullptr, nullptr, U_h, U_l, N);
        // h = relu(U @ U2 + b2u) -> h pair
        k_mgemm<4, 128, false, true, false, false, true><<<dim3(gb, 2), 256, 0, stream>>>(
            U_h, U_l, nullptr, nullptr, 0,
            U2t_h + (size_t)l * 128 * 128, U2t_l + (size_t)l * 128 * 128,
            upd_b2 + (size_t)l * HD, nullptr, nullptr, nullptr, nullptr, h_h, h_l, N);
    }

    k_pool2<<<1024, 256, 0, stream>>>(h_h, h_l, batch, gsum, (unsigned int*)gmax, N);
    k_cls<<<G, 128, 0, stream>>>(gsum, gmax, gcnt, cW1, cb1, cW2, cb2, cW3, cb3,
                                 (float*)d_out);
}

// Round 7
// 813.767 us; speedup vs baseline: 1.4692x; 1.4297x over previous
//
#include <hip/hip_runtime.h>
#include <hip/hip_bf16.h>

#define HD 128
#define SCB 2048   // elements per scan block

typedef __attribute__((ext_vector_type(8))) short short8v;
typedef __attribute__((ext_vector_type(4))) float f32x4;
typedef unsigned short us;

__device__ __forceinline__ us f2bf(float f) {
    union { float f; unsigned u; } c; c.f = f;
    unsigned u = c.u;
    return (us)((u + 0x7fffu + ((u >> 16) & 1u)) >> 16);
}
__device__ __forceinline__ float bf2f(us b) {
    union { unsigned u; float f; } c; c.u = ((unsigned)b) << 16;
    return c.f;
}

// ---------------------------------------------------------------------------
// MFMA node GEMM, fp32 via bf16 hi/lo split (3 MFMA per logical fp32 term).
// Block: 512 threads = 8 waves; tile 64 rows x 128 cols (wave = 64r x 16c).
// A (hi+lo, full K) is LDS-staged ONCE per block with XOR swizzle
// (off ^ ((row&7)<<4)) so frag ds_read_b128 is ~2-way conflict (free).
// B (weights, transposed [col][K]) lives in registers per wave (L2-hot).
// Frag maps (HW-verified r5/r6): A row=lane&15, k=(lane>>4)*8+i;
// B col=lane&15 same k; D col=lane&15, row=(lane>>4)*4+reg.
// ---------------------------------------------------------------------------
template<int KSTEPS, int K1S, bool HASA2, bool RELU, bool DEGB, bool WF32, bool WBF>
__global__ __launch_bounds__(512) void k_mgemm(
    const us* __restrict__ A1h, const us* __restrict__ A1l,
    const us* __restrict__ A2h, const us* __restrict__ A2l,
    const us* __restrict__ Wth, const us* __restrict__ Wtl,
    const float* __restrict__ bias,
    const float* __restrict__ bdeg, const float* __restrict__ deg,
    float* __restrict__ Cf0, float* __restrict__ Cf1,
    us* __restrict__ Ch, us* __restrict__ Cl,
    int nrows)
{
    constexpr int K   = KSTEPS * 32;
    constexpr int CPR = K / 8;              // 16B chunks per row
    constexpr int ITER = (64 * CPR) / 512;  // staging chunks per thread
    __shared__ us As_h[64 * K];
    __shared__ us As_l[64 * K];

    const int tid  = threadIdx.x;
    const int wv   = tid >> 6;
    const int lane = tid & 63;
    const int r    = lane & 15;
    const int g    = lane >> 4;
    const int rb   = blockIdx.x * 64;
    const int col  = blockIdx.y * 128 + wv * 16 + r;

    // ---- B fragments for the whole K in registers (L2-hot, loaded once) ----
    short8v bh[KSTEPS], bl[KSTEPS];
    {
        size_t wbase = (size_t)col * K + (size_t)(g * 8);
#pragma unroll
        for (int s = 0; s < KSTEPS; ++s) {
            bh[s] = *(const short8v*)(Wth + wbase + s * 32);
            bl[s] = *(const short8v*)(Wtl + wbase + s * 32);
        }
    }

    // ---- stage A tile (64 rows x K, hi+lo) into LDS, swizzled ----
#pragma unroll
    for (int i = 0; i < ITER; ++i) {
        int f = tid + i * 512;
        int row = f / CPR, c = f % CPR;
        int grow = rb + row; if (grow >= nrows) grow = nrows - 1;
        uint4 vh, vl;
        if (!HASA2 || c * 8 < K1S) {
            size_t o = (size_t)grow * K1S + (size_t)(c * 8);
            vh = *(const uint4*)(A1h + o);
            vl = *(const uint4*)(A1l + o);
        } else {
            size_t o = (size_t)grow * (K - K1S) + (size_t)(c * 8 - K1S);
            vh = *(const uint4*)(A2h + o);
            vl = *(const uint4*)(A2l + o);
        }
        int boff = row * (K * 2) + ((c * 16) ^ ((row & 7) << 4));
        *(uint4*)((char*)As_h + boff) = vh;
        *(uint4*)((char*)As_l + boff) = vl;
    }
    __syncthreads();

    // ---- compute ----
    f32x4 acc[4];
#pragma unroll
    for (int t = 0; t < 4; ++t) acc[t] = (f32x4){0.f, 0.f, 0.f, 0.f};

#pragma unroll
    for (int s = 0; s < KSTEPS; ++s) {
#pragma unroll
        for (int t = 0; t < 4; ++t) {
            int row = t * 16 + r;
            int boff = row * (K * 2) + (((s * 64) + g * 16) ^ ((row & 7) << 4));
            short8v ah = *(const short8v*)((const char*)As_h + boff);
            short8v al = *(const short8v*)((const char*)As_l + boff);
            acc[t] = __builtin_amdgcn_mfma_f32_16x16x32_bf16(ah, bh[s], acc[t], 0, 0, 0);
            acc[t] = __builtin_amdgcn_mfma_f32_16x16x32_bf16(al, bh[s], acc[t], 0, 0, 0);
            acc[t] = __builtin_amdgcn_mfma_f32_16x16x32_bf16(ah, bl[s], acc[t], 0, 0, 0);
        }
    }

    // ---- epilogue ----
    const float bb = (bias && col < 128) ? bias[col] : 0.f;
    const float bd = (DEGB && col < 128) ? bdeg[col] : 0.f;
    const int jc = col & 127;
#pragma unroll
    for (int t = 0; t < 4; ++t) {
#pragma unroll
        for (int i = 0; i < 4; ++i) {
            int row = rb + t * 16 + g * 4 + i;
            if (row >= nrows) continue;
            float v = acc[t][i] + bb;
            if (DEGB) v += deg[row] * bd;
            if (RELU) v = fmaxf(v, 0.f);
            size_t o = (size_t)row * HD + jc;
            if (WF32) (col < 128 ? Cf0 : Cf1)[o] = v;
            if (WBF) {
                us hh = f2bf(v);
                Ch[o] = hh;
                Cl[o] = f2bf(v - bf2f(hh));
            }
        }
    }
}

// ---------------------------------------------------------------------------
// Conversions
// ---------------------------------------------------------------------------
__global__ void k_cvtA(const float* __restrict__ src,
                       us* __restrict__ dh, us* __restrict__ dl, long n)
{
    long i = (long)blockIdx.x * blockDim.x + threadIdx.x;
    if (i >= n) return;
    float v = src[i];
    us h = f2bf(v);
    dh[i] = h;
    dl[i] = f2bf(v - bf2f(h));
}

// transpose [K][128] fp32 -> [128 j][K] bf16 hi/lo (per layer via blockIdx.y)
__global__ void k_cvtW(const float* __restrict__ src, long sstride, int K,
                       us* __restrict__ dh, us* __restrict__ dl, long dstride)
{
    int l = blockIdx.y;
    int idx = blockIdx.x * 256 + threadIdx.x;
    if (idx >= K * 128) return;
    int k = idx >> 7, j = idx & 127;
    float v = src[(size_t)l * sstride + (size_t)k * 128 + j];
    us h = f2bf(v);
    size_t o = (size_t)l * dstride + (size_t)j * K + k;
    dh[o] = h;
    dl[o] = f2bf(v - bf2f(h));
}

// two-source variant: rows [0,K1s) from srcA, [K1s,K) from srcB
__global__ void k_cvtW2(const float* __restrict__ srcA, long strideA,
                        const float* __restrict__ srcB, long strideB,
                        int K1s, int K,
                        us* __restrict__ dh, us* __restrict__ dl, long dstride)
{
    int l = blockIdx.y;
    int idx = blockIdx.x * 256 + threadIdx.x;
    if (idx >= K * 128) return;
    int k = idx >> 7, j = idx & 127;
    float v = (k < K1s)
        ? srcA[(size_t)l * strideA + (size_t)k * 128 + j]
        : srcB[(size_t)l * strideB + (size_t)(k - K1s) * 128 + j];
    us h = f2bf(v);
    size_t o = (size_t)l * dstride + (size_t)j * K + k;
    dh[o] = h;
    dl[o] = f2bf(v - bf2f(h));
}

// ---------------------------------------------------------------------------
// CSR build: deg+hist -> 3-phase parallel scan -> scatter
// ---------------------------------------------------------------------------
__global__ void k_deghist(const int* __restrict__ dst, int* __restrict__ degi, int E,
                          const int* __restrict__ batch, int* __restrict__ gcnt, int N)
{
    int i = blockIdx.x * blockDim.x + threadIdx.x;
    if (i < E) atomicAdd(&degi[dst[i]], 1);
    if (i < N) atomicAdd(&gcnt[batch[i]], 1);
}

__global__ __launch_bounds__(256) void k_scan1(const int* __restrict__ degi,
                                               int* __restrict__ thrpre,
                                               int* __restrict__ bsum, int N)
{
    __shared__ int sc[256];
    const int t = threadIdx.x, b = blockIdx.x;
    int i0 = b * SCB + t * 8;
    int s = 0;
#pragma unroll
    for (int q = 0; q < 8; ++q) {
        int i = i0 + q;
        if (i < N) s += degi[i];
    }
    sc[t] = s;
    __syncthreads();
    for (int o = 1; o < 256; o <<= 1) {
        int v = (t >= o) ? sc[t - o] : 0;
        __syncthreads();
        sc[t] += v;
        __syncthreads();
    }
    thrpre[b * 256 + t] = sc[t] - s;
    if (t == 255) bsum[b] = sc[255];
}

__global__ void k_scan2(const int* __restrict__ bsum, int* __restrict__ boff, int nb)
{
    if (threadIdx.x == 0 && blockIdx.x == 0) {
        int run = 0;
        for (int b = 0; b < nb; ++b) { boff[b] = run; run += bsum[b]; }
    }
}

__global__ __launch_bounds__(256) void k_scan3(
    const int* __restrict__ degi, const int* __restrict__ thrpre,
    const int* __restrict__ boff,
    int* __restrict__ rowptr, int* __restrict__ cursor,
    float* __restrict__ degf, int N, int E)
{
    const int t = threadIdx.x, b = blockIdx.x;
    int run = boff[b] + thrpre[b * 256 + t];
    int i0 = b * SCB + t * 8;
#pragma unroll
    for (int q = 0; q < 8; ++q) {
        int i = i0 + q;
        if (i < N) {
            int d = degi[i];
            rowptr[i] = run;
            cursor[i] = run;
            degf[i] = (float)d;
            run += d;
        }
    }
    if (b == 0 && t == 0) rowptr[N] = E;
}

__global__ void k_scatter(const int* __restrict__ dst, const int* __restrict__ src,
                          int* __restrict__ cursor,
                          int* __restrict__ csr_src, int* __restrict__ csr_eid, int E)
{
    int e = blockIdx.x * blockDim.x + threadIdx.x;
    if (e < E) {
        int d = dst[e];
        int pos = atomicAdd(&cursor[d], 1);
        csr_src[pos] = src[e];
        csr_eid[pos] = e;
    }
}

__global__ void k_permEA(const float* __restrict__ ea, const int* __restrict__ csr_eid,
                         float* __restrict__ ea_p, int E)
{
    long long gid = (long long)blockIdx.x * blockDim.x + threadIdx.x;
    if (gid >= (long long)E * 4) return;
    int pos = (int)(gid >> 2), part = (int)(gid & 3);
    int e = csr_eid[pos];
    ((float4*)ea_p)[(size_t)pos * 4 + part] = ((const float4*)ea)[(size_t)e * 4 + part];
}

// ---------------------------------------------------------------------------
// Weight folds: fold = W2 @ U1b  (128x128 per layer) ; bvec2 = b2 @ U1b
// ---------------------------------------------------------------------------
__global__ __launch_bounds__(256) void k_foldW(
    const float* __restrict__ msg_W2, const float* __restrict__ upd_W1,
    float* __restrict__ fold)
{
    int l = blockIdx.x >> 3, rb = blockIdx.x & 7;
    const float* W2  = msg_W2 + (size_t)l * HD * HD;
    const float* U1b = upd_W1 + (size_t)l * 256 * HD + (size_t)HD * HD;
    float* Wout = fold + (size_t)l * HD * HD;
    int j = threadIdx.x & 127;
    int rh = threadIdx.x >> 7;
    int r0 = rb * 16 + rh * 8;
    float acc[8] = {0.f,0.f,0.f,0.f,0.f,0.f,0.f,0.f};
    for (int k = 0; k < HD; ++k) {
        float u = U1b[(size_t)k * HD + j];
#pragma unroll
        for (int rr = 0; rr < 8; ++rr)
            acc[rr] = fmaf(W2[(size_t)(r0 + rr) * HD + k], u, acc[rr]);
    }
#pragma unroll
    for (int rr = 0; rr < 8; ++rr)
        Wout[(size_t)(r0 + rr) * HD + j] = acc[rr];
}

__global__ __launch_bounds__(128) void k_foldb(
    const float* __restrict__ msg_b2, const float* __restrict__ upd_W1,
    float* __restrict__ bvec2)
{
    int l = blockIdx.x, j = threadIdx.x;
    const float* U1b = upd_W1 + (size_t)l * 256 * HD + (size_t)HD * HD;
    const float* b2 = msg_b2 + (size_t)l * HD;
    float acc = 0.f;
    for (int k = 0; k < HD; ++k) acc = fmaf(b2[k], U1b[(size_t)k * HD + j], acc);
    bvec2[(size_t)l * HD + j] = acc;
}

// ---------------------------------------------------------------------------
// Edge gather: S[n] = sum_{e:dst=n} relu(P[n] + Q[src] + ea@Wc)
// wave per node; 4-edge unroll. Output written as bf16 hi/lo pair.
// ---------------------------------------------------------------------------
template<bool PERM>
__global__ __launch_bounds__(256) void k_edge(
    const float* __restrict__ P, const float* __restrict__ Q,
    const float* __restrict__ EA,
    const int* __restrict__ rowptr,
    const int* __restrict__ csr_src, const int* __restrict__ csr_eid,
    const float* __restrict__ W1c,
    us* __restrict__ Sh, us* __restrict__ Sl, int N)
{
    const int lane = threadIdx.x & 63;
    const int node = blockIdx.x * 4 + (threadIdx.x >> 6);
    if (node >= N) return;
    float wA[16], wB[16];
#pragma unroll
    for (int k = 0; k < 16; ++k) {
        wA[k] = W1c[k * HD + lane];
        wB[k] = W1c[k * HD + 64 + lane];
    }
    const int beg = rowptr[node], end = rowptr[node + 1];
    const float pA = P[(size_t)node * HD + lane];
    const float pB = P[(size_t)node * HD + 64 + lane];
    float accA = 0.f, accB = 0.f;

    int i = beg;
    for (; i + 4 <= end; i += 4) {
        int s[4];
        s[0] = csr_src[i]; s[1] = csr_src[i + 1];
        s[2] = csr_src[i + 2]; s[3] = csr_src[i + 3];
        float qA[4], qB[4];
#pragma unroll
        for (int r2 = 0; r2 < 4; ++r2) {
            qA[r2] = Q[(size_t)s[r2] * HD + lane];
            qB[r2] = Q[(size_t)s[r2] * HD + 64 + lane];
        }
#pragma unroll
        for (int r2 = 0; r2 < 4; ++r2) {
            const float4* Ev = PERM ? (const float4*)&EA[(size_t)(i + r2) * 16]
                                    : (const float4*)&EA[(size_t)csr_eid[i + r2] * 16];
            float4 v0 = Ev[0], v1 = Ev[1], v2 = Ev[2], v3 = Ev[3];
            float tA = pA + qA[r2], tB = pB + qB[r2];
            tA = fmaf(v0.x, wA[0],  tA); tB = fmaf(v0.x, wB[0],  tB);
            tA = fmaf(v0.y, wA[1],  tA); tB = fmaf(v0.y, wB[1],  tB);
            tA = fmaf(v0.z, wA[2],  tA); tB = fmaf(v0.z, wB[2],  tB);
            tA = fmaf(v0.w, wA[3],  tA); tB = fmaf(v0.w, wB[3],  tB);
            tA = fmaf(v1.x, wA[4],  tA); tB = fmaf(v1.x, wB[4],  tB);
            tA = fmaf(v1.y, wA[5],  tA); tB = fmaf(v1.y, wB[5],  tB);
            tA = fmaf(v1.z, wA[6],  tA); tB = fmaf(v1.z, wB[6],  tB);
            tA = fmaf(v1.w, wA[7],  tA); tB = fmaf(v1.w, wB[7],  tB);
            tA = fmaf(v2.x, wA[8],  tA); tB = fmaf(v2.x, wB[8],  tB);
            tA = fmaf(v2.y, wA[9],  tA); tB = fmaf(v2.y, wB[9],  tB);
            tA = fmaf(v2.z, wA[10], tA); tB = fmaf(v2.z, wB[10], tB);
            tA = fmaf(v2.w, wA[11], tA); tB = fmaf(v2.w, wB[11], tB);
            tA = fmaf(v3.x, wA[12], tA); tB = fmaf(v3.x, wB[12], tB);
            tA = fmaf(v3.y, wA[13], tA); tB = fmaf(v3.y, wB[13], tB);
            tA = fmaf(v3.z, wA[14], tA); tB = fmaf(v3.z, wB[14], tB);
            tA = fmaf(v3.w, wA[15], tA); tB = fmaf(v3.w, wB[15], tB);
            accA += fmaxf(tA, 0.f);
            accB += fmaxf(tB, 0.f);
        }
    }
    for (; i < end; ++i) {
        int s0 = csr_src[i];
        float qA0 = Q[(size_t)s0 * HD + lane];
        float qB0 = Q[(size_t)s0 * HD + 64 + lane];
        const float4* Ev = PERM ? (const float4*)&EA[(size_t)i * 16]
                                : (const float4*)&EA[(size_t)csr_eid[i] * 16];
        float4 v0 = Ev[0], v1 = Ev[1], v2 = Ev[2], v3 = Ev[3];
        float tA = pA + qA0, tB = pB + qB0;
        tA = fmaf(v0.x, wA[0],  tA); tB = fmaf(v0.x, wB[0],  tB);
        tA = fmaf(v0.y, wA[1],  tA); tB = fmaf(v0.y, wB[1],  tB);
        tA = fmaf(v0.z, wA[2],  tA); tB = fmaf(v0.z, wB[2],  tB);
        tA = fmaf(v0.w, wA[3],  tA); tB = fmaf(v0.w, wB[3],  tB);
        tA = fmaf(v1.x, wA[4],  tA); tB = fmaf(v1.x, wB[4],  tB);
        tA = fmaf(v1.y, wA[5],  tA); tB = fmaf(v1.y, wB[5],  tB);
        tA = fmaf(v1.z, wA[6],  tA); tB = fmaf(v1.z, wB[6],  tB);
        tA = fmaf(v1.w, wA[7],  tA); tB = fmaf(v1.w, wB[7],  tB);
        tA = fmaf(v2.x, wA[8],  tA); tB = fmaf(v2.x, wB[8],  tB);
        tA = fmaf(v2.y, wA[9],  tA); tB = fmaf(v2.y, wB[9],  tB);
        tA = fmaf(v2.z, wA[10], tA); tB = fmaf(v2.z, wB[10], tB);
        tA = fmaf(v2.w, wA[11], tA); tB = fmaf(v2.w, wB[11], tB);
        tA = fmaf(v3.x, wA[12], tA); tB = fmaf(v3.x, wB[12], tB);
        tA = fmaf(v3.y, wA[13], tA); tB = fmaf(v3.y, wB[13], tB);
        tA = fmaf(v3.z, wA[14], tA); tB = fmaf(v3.z, wB[14], tB);
        tA = fmaf(v3.w, wA[15], tA); tB = fmaf(v3.w, wB[15], tB);
        accA += fmaxf(tA, 0.f);
        accB += fmaxf(tB, 0.f);
    }
    size_t oA = (size_t)node * HD + lane;
    size_t oB = oA + 64;
    us hA = f2bf(accA);
    us hB = f2bf(accB);
    Sh[oA] = hA; Sl[oA] = f2bf(accA - bf2f(hA));
    Sh[oB] = hB; Sl[oB] = f2bf(accB - bf2f(hB));
}

// ---------------------------------------------------------------------------
// Pool (segment mean/max over sorted batch) from bf16 hi/lo h; then classifier.
// ---------------------------------------------------------------------------
__global__ __launch_bounds__(256) void k_pool2(
    const us* __restrict__ hh, const us* __restrict__ hl,
    const int* __restrict__ batch,
    float* __restrict__ gsum, unsigned int* __restrict__ gmax, int N)
{
    int nchunk = (N + gridDim.x - 1) / gridDim.x;
    int n0 = blockIdx.x * nchunk;
    int n1 = n0 + nchunk; if (n1 > N) n1 = N;
    int j = threadIdx.x & 127;
    int half = threadIdx.x >> 7;
    float s = 0.f, m = 0.f; int gcur = -1;
    for (int n = n0 + half; n < n1; n += 2) {
        int g = batch[n];
        if (g != gcur) {
            if (gcur >= 0) {
                atomicAdd(&gsum[(size_t)gcur * HD + j], s);
                atomicMax(&gmax[(size_t)gcur * HD + j], __float_as_uint(m));
            }
            gcur = g; s = 0.f; m = 0.f;
        }
        size_t o = (size_t)n * HD + j;
        float v = bf2f(hh[o]) + bf2f(hl[o]);
        s += v; m = fmaxf(m, v);
    }
    if (gcur >= 0) {
        atomicAdd(&gsum[(size_t)gcur * HD + j], s);
        atomicMax(&gmax[(size_t)gcur * HD + j], __float_as_uint(m));
    }
}

__global__ __launch_bounds__(128) void k_cls(
    const float* __restrict__ gsum, const float* __restrict__ gmax,
    const int* __restrict__ gcnt,
    const float* __restrict__ W1, const float* __restrict__ b1,
    const float* __restrict__ W2, const float* __restrict__ b2,
    const float* __restrict__ W3, const float* __restrict__ b3,
    float* __restrict__ out)
{
    __shared__ float rep[256];
    __shared__ float z1[128];
    __shared__ float z2[64];
    const int g = blockIdx.x;
    const int j = threadIdx.x;
    float cntf = (float)gcnt[g];
    rep[j]       = gsum[(size_t)g * HD + j] / fmaxf(cntf, 1.f);
    rep[128 + j] = gmax[(size_t)g * HD + j];
    __syncthreads();
    float a = 0.f;
    for (int k = 0; k < 256; ++k) a = fmaf(rep[k], W1[(size_t)k * 128 + j], a);
    z1[j] = fmaxf(a + b1[j], 0.f);
    __syncthreads();
    if (j < 64) {
        float b = 0.f;
        for (int k = 0; k < 128; ++k) b = fmaf(z1[k], W2[(size_t)k * 64 + j], b);
        z2[j] = fmaxf(b + b2[j], 0.f);
    }
    __syncthreads();
    if (j < 2) {
        float c = 0.f;
        for (int k = 0; k < 64; ++k) c = fmaf(z2[k], W3[(size_t)k * 2 + j], c);
        out[(size_t)g * 2 + j] = c + b3[j];
    }
}

extern "C" void kernel_launch(void* const* d_in, const int* in_sizes, int n_in,
                              void* d_out, int out_size, void* d_ws, size_t ws_size,
                              hipStream_t stream) {
    const float* x      = (const float*)d_in[0];
    const float* ea     = (const float*)d_in[1];
    const int*   ei     = (const int*)d_in[2];
    const int*   batch  = (const int*)d_in[3];
    const float* emb_W  = (const float*)d_in[4];
    const float* emb_b  = (const float*)d_in[5];
    const float* msg_W1 = (const float*)d_in[6];
    const float* msg_b1 = (const float*)d_in[7];
    const float* msg_W2 = (const float*)d_in[8];
    const float* msg_b2 = (const float*)d_in[9];
    const float* upd_W1 = (const float*)d_in[10];
    const float* upd_b1 = (const float*)d_in[11];
    const float* upd_W2 = (const float*)d_in[12];
    const float* upd_b2 = (const float*)d_in[13];
    const float* cW1 = (const float*)d_in[14];
    const float* cb1 = (const float*)d_in[15];
    const float* cW2 = (const float*)d_in[16];
    const float* cb2 = (const float*)d_in[17];
    const float* cW3 = (const float*)d_in[18];
    const float* cb3 = (const float*)d_in[19];

    const int N = in_sizes[0] / 64;
    const int E = in_sizes[1] / 16;
    const int G = 256, L = 3;
    const int* src = ei;
    const int* dst = ei + E;
    const int nb = (N + SCB - 1) / SCB;

    char* w = (char*)d_ws;
    size_t off = 0;
    auto alloc = [&](size_t bytes) -> void* {
        void* p = w + off;
        off += (bytes + 255) & ~(size_t)255;
        return p;
    };
    float* Pb  = (float*)alloc((size_t)N * HD * 4);  // P fp32; aliased as U pair
    float* Qb  = (float*)alloc((size_t)N * HD * 4);  // Q fp32
    us* S_h = (us*)alloc((size_t)N * HD * 2);        // S hi; aliased as x_h
    us* S_l = (us*)alloc((size_t)N * HD * 2);        // S lo; aliased as x_l
    us* h_h = (us*)alloc((size_t)N * HD * 2);
    us* h_l = (us*)alloc((size_t)N * HD * 2);
    us* U_h = (us*)Pb;                               // alias: U pair over Pb
    us* U_l = U_h + (size_t)N * HD;
    us* x_h = S_h;                                   // alias: x pair over S pair
    us* x_l = S_l;
    float* fold  = (float*)alloc((size_t)L * HD * HD * 4);
    float* bvec2 = (float*)alloc((size_t)L * HD * 4);
    us* embt_h = (us*)alloc((size_t)128 * 64 * 2);
    us* embt_l = (us*)alloc((size_t)128 * 64 * 2);
    us* WPQt_h = (us*)alloc((size_t)L * 256 * 128 * 2);  // [256 j][128 k]
    us* WPQt_l = (us*)alloc((size_t)L * 256 * 128 * 2);
    us* Wcbt_h = (us*)alloc((size_t)L * 128 * 256 * 2);  // [128 j][256 k]
    us* Wcbt_l = (us*)alloc((size_t)L * 128 * 256 * 2);
    us* U2t_h  = (us*)alloc((size_t)L * 128 * 128 * 2);
    us* U2t_l  = (us*)alloc((size_t)L * 128 * 128 * 2);
    int*   degi   = (int*)alloc((size_t)N * 4);
    float* degf   = (float*)alloc((size_t)N * 4);
    int*   rowptr = (int*)alloc((size_t)(N + 1) * 4);
    int*   cursor = (int*)alloc((size_t)N * 4);
    int*   thrpre = (int*)alloc((size_t)nb * 256 * 4);
    int*   bsum   = (int*)alloc((size_t)(nb + 1) * 4);
    int*   boff   = (int*)alloc((size_t)(nb + 1) * 4);
    int*   gcnt   = (int*)alloc(256 * 4);
    float* gsum   = (float*)alloc((size_t)G * HD * 4);
    float* gmax   = (float*)alloc((size_t)G * HD * 4);
    int*   csr_src = (int*)alloc((size_t)E * 4);
    int*   csr_eid = (int*)alloc((size_t)E * 4);
    float* ea_p = nullptr;
    if (ws_size && off + (size_t)E * 16 * 4 + 256 <= ws_size)
        ea_p = (float*)alloc((size_t)E * 16 * 4);
    (void)n_in; (void)out_size;

    hipMemsetAsync(degi, 0, (size_t)N * 4, stream);
    hipMemsetAsync(gcnt, 0, 256 * 4, stream);
    hipMemsetAsync(gsum, 0, (size_t)G * HD * 4, stream);
    hipMemsetAsync(gmax, 0, (size_t)G * HD * 4, stream);

    // ---- CSR build (parallel scan) ----
    int mEN = (E > N ? E : N);
    k_deghist<<<(mEN + 255) / 256, 256, 0, stream>>>(dst, degi, E, batch, gcnt, N);
    k_scan1<<<nb, 256, 0, stream>>>(degi, thrpre, bsum, N);
    k_scan2<<<1, 64, 0, stream>>>(bsum, boff, nb);
    k_scan3<<<nb, 256, 0, stream>>>(degi, thrpre, boff, rowptr, cursor, degf, N, E);
    k_scatter<<<(E + 255) / 256, 256, 0, stream>>>(dst, src, cursor, csr_src, csr_eid, E);
    if (ea_p)
        k_permEA<<<(int)(((long long)E * 4 + 255) / 256), 256, 0, stream>>>(ea, csr_eid, ea_p, E);

    // ---- weight folds + conversions ----
    k_foldW<<<L * 8, 256, 0, stream>>>(msg_W2, upd_W1, fold);
    k_foldb<<<L, 128, 0, stream>>>(msg_b2, upd_W1, bvec2);

    k_cvtA<<<(int)(((long)N * 64 + 255) / 256), 256, 0, stream>>>(x, x_h, x_l, (long)N * 64);
    k_cvtW<<<dim3(32, 1), 256, 0, stream>>>(emb_W, 0, 64, embt_h, embt_l, 0);
    // [Wa|Wb] -> WPQt [256 j][128 k]: Wa into j<128, Wb into j>=128
    k_cvtW<<<dim3(64, L), 256, 0, stream>>>(msg_W1, 272 * 128, 128,
                                            WPQt_h, WPQt_l, 256 * 128);
    k_cvtW<<<dim3(64, L), 256, 0, stream>>>(msg_W1 + 128 * 128, 272 * 128, 128,
                                            WPQt_h + 128 * 128, WPQt_l + 128 * 128,
                                            256 * 128);
    // Wcbt: k<128 from U1a (upd_W1 rows 0..127), k>=128 from fold (W2@U1b)
    k_cvtW2<<<dim3(128, L), 256, 0, stream>>>(upd_W1, 256 * 128, fold, 128 * 128,
                                              128, 256, Wcbt_h, Wcbt_l, 128 * 256);
    k_cvtW<<<dim3(64, L), 256, 0, stream>>>(upd_W2, 128 * 128, 128,
                                            U2t_h, U2t_l, 128 * 128);

    const int gb = (N + 63) / 64;
    // ---- embed: h = x @ emb_W + emb_b (no relu) -> h pair ----
    k_mgemm<2, 64, false, false, false, false, true><<<dim3(gb, 1), 512, 0, stream>>>(
        x_h, x_l, nullptr, nullptr, embt_h, embt_l,
        emb_b, nullptr, nullptr, nullptr, nullptr, h_h, h_l, N);

    for (int l = 0; l < L; ++l) {
        const float* W1 = msg_W1 + (size_t)l * 272 * HD;
        // [P|Q] = h @ [Wa|Wb] (+b1 on P cols) -> Pb, Qb fp32, one dispatch
        k_mgemm<4, 128, false, false, false, true, false><<<dim3(gb, 2), 512, 0, stream>>>(
            h_h, h_l, nullptr, nullptr,
            WPQt_h + (size_t)l * 256 * 128, WPQt_l + (size_t)l * 256 * 128,
            msg_b1 + (size_t)l * HD, nullptr, nullptr, Pb, Qb, nullptr, nullptr, N);
        // S[n] = sum_in relu(P[n] + Q[src] + ea@Wc) -> bf16 pair
        if (ea_p)
            k_edge<true><<<(N + 3) / 4, 256, 0, stream>>>(Pb, Qb, ea_p, rowptr,
                                                          csr_src, nullptr,
                                                          W1 + 256 * HD, S_h, S_l, N);
        else
            k_edge<false><<<(N + 3) / 4, 256, 0, stream>>>(Pb, Qb, ea, rowptr,
                                                           csr_src, csr_eid,
                                                           W1 + 256 * HD, S_h, S_l, N);
        // U = relu([h|S] @ [U1a; W2@U1b] + b1u + deg*bvec2) -> U pair
        k_mgemm<8, 128, true, true, true, false, true><<<dim3(gb, 1), 512, 0, stream>>>(
            h_h, h_l, S_h, S_l,
            Wcbt_h + (size_t)l * 128 * 256, Wcbt_l + (size_t)l * 128 * 256,
            upd_b1 + (size_t)l * HD, bvec2 + (size_t)l * HD, degf,
            nullptr, nullptr, U_h, U_l, N);
        // h = relu(U @ U2 + b2u) -> h pair
        k_mgemm<4, 128, false, true, false, false, true><<<dim3(gb, 1), 512, 0, stream>>>(
            U_h, U_l, nullptr, nullptr,
            U2t_h + (size_t)l * 128 * 128, U2t_l + (size_t)l * 128 * 128,
            upd_b2 + (size_t)l * HD, nullptr, nullptr, nullptr, nullptr, h_h, h_l, N);
    }

    k_pool2<<<1024, 256, 0, stream>>>(h_h, h_l, batch, gsum, (unsigned int*)gmax, N);
    k_cls<<<G, 128, 0, stream>>>(gsum, gmax, gcnt, cW1, cb1, cW2, cb2, cW3, cb3,
                                 (float*)d_out);
}